// Round 1
// baseline (65.868 us; speedup 1.0000x reference)
//
#include <hip/hip_runtime.h>
#include <math.h>

#define NNODES   100000
#define S        8192
#define D        8
#define NEDGES   1000000
#define EPSF     1e-6f

// ws layout (floats)
#define ZS_OFF   0            // 8192*8 = 65536
#define U_OFF    65536        // 8192
#define V_OFF    73728        // 8192
#define DP_OFF   81920        // 1024 dense partials
#define SP_OFF   82944        // 1024 sparse partials
// total 83968 floats = 335872 bytes

#define DENSE_GX 32           // i-chunks of 256
#define DENSE_GY 32           // j-chunks of JT
#define JT       256          // j-tile rows per block
#define SPARSE_NB 1024

__device__ __forceinline__ float block_reduce_f(float v, float* sm) {
    #pragma unroll
    for (int off = 32; off > 0; off >>= 1) v += __shfl_down(v, off, 64);
    int lane = threadIdx.x & 63, wid = threadIdx.x >> 6;
    if (lane == 0) sm[wid] = v;
    __syncthreads();
    float s = 0.f;
    if (threadIdx.x == 0) {
        int nw = blockDim.x >> 6;
        for (int w = 0; w < nw; ++w) s += sm[w];
    }
    return s;
}

// Gather sampled rows into packed zs, precompute u_i, v_j.
__global__ __launch_bounds__(256) void gather_kernel(const float* __restrict__ Z,
                                                     const int* __restrict__ idx,
                                                     float* __restrict__ zs,
                                                     float* __restrict__ u,
                                                     float* __restrict__ v) {
    int t = blockIdx.x * blockDim.x + threadIdx.x;
    if (t >= S) return;
    int n = idx[t];
    const float4* zp = (const float4*)(Z + (size_t)n * D);
    float4 a = zp[0], b = zp[1];
    ((float4*)(zs + (size_t)t * D))[0] = a;
    ((float4*)(zs + (size_t)t * D))[1] = b;
    float ss = a.x*a.x + a.y*a.y + a.z*a.z + a.w*a.w
             + b.x*b.x + b.y*b.y + b.z*b.z + b.w*b.w;
    float sl = a.x + a.y + a.z + a.w + b.x + b.y + b.z + b.w;
    u[t] = ss + 2.f * EPSF * sl + (float)D * EPSF * EPSF;
    v[t] = ss - 2.f * EPSF * sl;
}

// Dense off-diagonal sum of exp(-||zi - zj + eps||) over the sampled subgraph.
__global__ __launch_bounds__(256) void dense_kernel(const float* __restrict__ zs,
                                                    const float* __restrict__ u,
                                                    const float* __restrict__ v,
                                                    float* __restrict__ part) {
    __shared__ float tile[JT * D];   // 8 KB
    __shared__ float vt[JT];         // 1 KB
    __shared__ float red[4];

    int tid = threadIdx.x;
    int i   = blockIdx.x * 256 + tid;
    int j0  = blockIdx.y * JT;

    // my row + u_i
    const float4* zr = (const float4*)(zs + (size_t)i * D);
    float4 r0 = zr[0], r1 = zr[1];
    float zi[8] = { r0.x, r0.y, r0.z, r0.w, r1.x, r1.y, r1.z, r1.w };
    float ui = u[i];

    // stage j-tile: JT*8 floats = 512 float4, 256 threads -> 2 each
    const float4* src = (const float4*)(zs + (size_t)j0 * D);
    float4* dst = (float4*)tile;
    dst[tid]       = src[tid];
    dst[tid + 256] = src[tid + 256];
    vt[tid] = v[j0 + tid];
    __syncthreads();

    float acc = 0.f;
    #pragma unroll 8
    for (int jj = 0; jj < JT; ++jj) {
        const float* zj = tile + jj * D;
        float dot = zi[0] * zj[0];
        dot = fmaf(zi[1], zj[1], dot);
        dot = fmaf(zi[2], zj[2], dot);
        dot = fmaf(zi[3], zj[3], dot);
        dot = fmaf(zi[4], zj[4], dot);
        dot = fmaf(zi[5], zj[5], dot);
        dot = fmaf(zi[6], zj[6], dot);
        dot = fmaf(zi[7], zj[7], dot);
        float d2 = ui + vt[jj] - 2.f * dot;
        d2 = fmaxf(d2, 0.f);
        float w = __expf(-__fsqrt_rn(d2));
        acc += (j0 + jj == i) ? 0.f : w;
    }

    float s = block_reduce_f(acc, red);
    if (tid == 0) part[blockIdx.x * DENSE_GY + blockIdx.y] = s;
}

// Sparse positive-edge distances.
__global__ __launch_bounds__(256) void sparse_kernel(const float* __restrict__ Z,
                                                     const int* __restrict__ ei,
                                                     const int* __restrict__ ej,
                                                     float* __restrict__ part) {
    __shared__ float red[4];
    float acc = 0.f;
    int stride = gridDim.x * blockDim.x;
    for (int e = blockIdx.x * blockDim.x + threadIdx.x; e < NEDGES; e += stride) {
        int a = ei[e], b = ej[e];
        const float4* za = (const float4*)(Z + (size_t)a * D);
        const float4* zb = (const float4*)(Z + (size_t)b * D);
        float4 a0 = za[0], a1 = za[1];
        float4 b0 = zb[0], b1 = zb[1];
        float d0 = a0.x - b0.x + EPSF;
        float d1 = a0.y - b0.y + EPSF;
        float d2 = a0.z - b0.z + EPSF;
        float d3 = a0.w - b0.w + EPSF;
        float d4 = a1.x - b1.x + EPSF;
        float d5 = a1.y - b1.y + EPSF;
        float d6 = a1.z - b1.z + EPSF;
        float d7 = a1.w - b1.w + EPSF;
        float s2 = d0*d0;
        s2 = fmaf(d1, d1, s2);
        s2 = fmaf(d2, d2, s2);
        s2 = fmaf(d3, d3, s2);
        s2 = fmaf(d4, d4, s2);
        s2 = fmaf(d5, d5, s2);
        s2 = fmaf(d6, d6, s2);
        s2 = fmaf(d7, d7, s2);
        acc += __fsqrt_rn(s2);
    }
    float s = block_reduce_f(acc, red);
    if (threadIdx.x == 0) part[blockIdx.x] = s;
}

// Final: double-precision reduce of partials, compose scalar.
__global__ __launch_bounds__(256) void final_kernel(const float* __restrict__ alpha,
                                                    const float* __restrict__ dpart,
                                                    const float* __restrict__ spart,
                                                    float* __restrict__ out) {
    __shared__ double rd[4], rs[4];
    double ds = 0.0, ss = 0.0;
    for (int k = threadIdx.x; k < DENSE_GX * DENSE_GY; k += blockDim.x) ds += (double)dpart[k];
    for (int k = threadIdx.x; k < SPARSE_NB; k += blockDim.x)           ss += (double)spart[k];
    #pragma unroll
    for (int off = 32; off > 0; off >>= 1) {
        ds += __shfl_down(ds, off, 64);
        ss += __shfl_down(ss, off, 64);
    }
    int lane = threadIdx.x & 63, wid = threadIdx.x >> 6;
    if (lane == 0) { rd[wid] = ds; rs[wid] = ss; }
    __syncthreads();
    if (threadIdx.x == 0) {
        double Dsum = 0.0, Ssum = 0.0;
        for (int w = 0; w < 4; ++w) { Dsum += rd[w]; Ssum += rs[w]; }
        double a = (double)alpha[0];
        double z_pdist2 = (double)NEDGES * a - Ssum;
        // ones_exp_sq = exp(1)^2
        double z_pdist1 = exp(a) * 0.5 * 7.3890560989306495 * Dsum;
        out[0] = (float)(z_pdist2 - z_pdist1);
    }
}

extern "C" void kernel_launch(void* const* d_in, const int* in_sizes, int n_in,
                              void* d_out, int out_size, void* d_ws, size_t ws_size,
                              hipStream_t stream) {
    const float* latent_Z = (const float*)d_in[0];
    const float* alpha    = (const float*)d_in[1];
    const int*   sidx     = (const int*)d_in[2];
    const int*   ei       = (const int*)d_in[3];
    const int*   ej       = (const int*)d_in[4];
    float* out = (float*)d_out;
    float* ws  = (float*)d_ws;

    float* zs    = ws + ZS_OFF;
    float* u     = ws + U_OFF;
    float* v     = ws + V_OFF;
    float* dpart = ws + DP_OFF;
    float* spart = ws + SP_OFF;

    gather_kernel<<<S / 256, 256, 0, stream>>>(latent_Z, sidx, zs, u, v);
    dense_kernel<<<dim3(DENSE_GX, DENSE_GY), 256, 0, stream>>>(zs, u, v, dpart);
    sparse_kernel<<<SPARSE_NB, 256, 0, stream>>>(latent_Z, ei, ej, spart);
    final_kernel<<<1, 256, 0, stream>>>(alpha, dpart, spart, out);
}

// Round 3
// 49.637 us; speedup vs baseline: 1.3270x; 1.3270x over previous
//
#include <hip/hip_runtime.h>
#include <hip/hip_bf16.h>
#include <math.h>

#define NNODES   100000
#define S        8192
#define D        8
#define NEDGES   1000000
#define EPSF     1e-6f
#define LOG2E    1.442695040888963f

// ws byte offsets
#define ZH_OFF   0          // 8192*8 ushort = 131072 B
#define ZL_OFF   131072     // 8192*8 ushort
#define U_OFF    262144     // 8192 f32
#define V_OFF    294912     // 8192 f32
#define DP_OFF   327680     // 2048 f32 dense partials
#define SP_OFF   335872     // 1024 f32 sparse partials
// total 339968 B

#define JSPLIT   4
#define NDP      (512 * JSPLIT)
#define SPARSE_NB 1024

typedef __attribute__((ext_vector_type(8))) short short8_t;
typedef __attribute__((ext_vector_type(4))) float f32x4;

__device__ __forceinline__ float block_reduce_f(float v, float* sm) {
    #pragma unroll
    for (int off = 32; off > 0; off >>= 1) v += __shfl_down(v, off, 64);
    int lane = threadIdx.x & 63, wid = threadIdx.x >> 6;
    if (lane == 0) sm[wid] = v;
    __syncthreads();
    float s = 0.f;
    if (threadIdx.x == 0) {
        int nw = blockDim.x >> 6;
        for (int w = 0; w < nw; ++w) s += sm[w];
    }
    return s;
}

// Gather sampled rows; split each float into bf16 hi + bf16 lo; precompute u_i, v_j.
__global__ __launch_bounds__(256) void gather_kernel(const float* __restrict__ Z,
                                                     const int* __restrict__ idx,
                                                     ushort* __restrict__ zh,
                                                     ushort* __restrict__ zl,
                                                     float* __restrict__ u,
                                                     float* __restrict__ v) {
    int t = blockIdx.x * blockDim.x + threadIdx.x;
    if (t >= S) return;
    int n = idx[t];
    const float4* zp = (const float4*)(Z + (size_t)n * D);
    float4 a = zp[0], b = zp[1];
    float z[8] = { a.x, a.y, a.z, a.w, b.x, b.y, b.z, b.w };
    float ss = 0.f, sl = 0.f;
    short8_t h, l;
    #pragma unroll
    for (int k = 0; k < 8; ++k) {
        ss = fmaf(z[k], z[k], ss);
        sl += z[k];
        __hip_bfloat16 hb = __float2bfloat16(z[k]);
        float hf = __bfloat162float(hb);
        __hip_bfloat16 lb = __float2bfloat16(z[k] - hf);
        h[k] = (short)__builtin_bit_cast(unsigned short, hb);
        l[k] = (short)__builtin_bit_cast(unsigned short, lb);
    }
    *(short8_t*)(zh + (size_t)t * 8) = h;
    *(short8_t*)(zl + (size_t)t * 8) = l;
    u[t] = ss + 2.f * EPSF * sl + (float)D * EPSF * EPSF;
    v[t] = ss - 2.f * EPSF * sl;
}

// Dense: full sum of exp(-||zi - zj + eps||) over S x S (trace subtracted later).
// Gram dots via mfma_f32_16x16x32_bf16 with hi/lo K-packing:
//   A K-slots (k-group g = lane>>4): even g -> hi row, odd g -> lo row
//   B K-slots: g<2 -> hi row, g>=2 -> lo row
// => C = hi.hi + lo.hi + hi.lo + lo.lo = exact (hi+lo).(hi+lo)
__global__ __launch_bounds__(256) void dense_kernel(const ushort* __restrict__ zh,
                                                    const ushort* __restrict__ zl,
                                                    const float* __restrict__ u,
                                                    const float* __restrict__ v,
                                                    float* __restrict__ part) {
    __shared__ float red[4];
    int tid  = threadIdx.x;
    int wave = tid >> 6, lane = tid & 63;
    int g = lane >> 4, r = lane & 15;

    int i0 = blockIdx.x * 16;
    const int ntiles = 512 / JSPLIT / 4;                 // 32 j-tiles per wave
    int jt0 = blockIdx.y * (512 / JSPLIT) + wave * ntiles;

    // A fragment: row i0+r; k-group g even -> hi, odd -> lo. Fixed for whole sweep.
    const ushort* abase = (g & 1) ? zl : zh;
    short8_t afrag = *(const short8_t*)(abase + (size_t)(i0 + r) * 8);

    // epilogue u for my C rows: i = i0 + g*4 + q
    float4 u4 = *(const float4*)(u + i0 + g * 4);

    const ushort* bbase = (g < 2) ? zh : zl;

    float acc = 0.f;
    #pragma unroll 2
    for (int t = 0; t < ntiles; ++t) {
        int j0 = (jt0 + t) * 16;
        short8_t bfrag = *(const short8_t*)(bbase + (size_t)(j0 + r) * 8);
        float vt = v[j0 + r];                            // C col = r
        f32x4 c = { 0.f, 0.f, 0.f, 0.f };
        c = __builtin_amdgcn_mfma_f32_16x16x32_bf16(afrag, bfrag, c, 0, 0, 0);
        float s0 = u4.x + vt, s1 = u4.y + vt, s2 = u4.z + vt, s3 = u4.w + vt;
        float d2_0 = fmaxf(fmaf(c[0], -2.f, s0), 0.f);
        float d2_1 = fmaxf(fmaf(c[1], -2.f, s1), 0.f);
        float d2_2 = fmaxf(fmaf(c[2], -2.f, s2), 0.f);
        float d2_3 = fmaxf(fmaf(c[3], -2.f, s3), 0.f);
        acc += __builtin_amdgcn_exp2f(__builtin_amdgcn_sqrtf(d2_0) * (-LOG2E));
        acc += __builtin_amdgcn_exp2f(__builtin_amdgcn_sqrtf(d2_1) * (-LOG2E));
        acc += __builtin_amdgcn_exp2f(__builtin_amdgcn_sqrtf(d2_2) * (-LOG2E));
        acc += __builtin_amdgcn_exp2f(__builtin_amdgcn_sqrtf(d2_3) * (-LOG2E));
    }

    float s = block_reduce_f(acc, red);
    if (tid == 0) part[blockIdx.y * 512 + blockIdx.x] = s;
}

// Sparse positive-edge distances.
__global__ __launch_bounds__(256) void sparse_kernel(const float* __restrict__ Z,
                                                     const int* __restrict__ ei,
                                                     const int* __restrict__ ej,
                                                     float* __restrict__ part) {
    __shared__ float red[4];
    float acc = 0.f;
    int stride = gridDim.x * blockDim.x;
    for (int e = blockIdx.x * blockDim.x + threadIdx.x; e < NEDGES; e += stride) {
        int a = ei[e], b = ej[e];
        const float4* za = (const float4*)(Z + (size_t)a * D);
        const float4* zb = (const float4*)(Z + (size_t)b * D);
        float4 a0 = za[0], a1 = za[1];
        float4 b0 = zb[0], b1 = zb[1];
        float d0 = a0.x - b0.x + EPSF;
        float d1 = a0.y - b0.y + EPSF;
        float d2 = a0.z - b0.z + EPSF;
        float d3 = a0.w - b0.w + EPSF;
        float d4 = a1.x - b1.x + EPSF;
        float d5 = a1.y - b1.y + EPSF;
        float d6 = a1.z - b1.z + EPSF;
        float d7 = a1.w - b1.w + EPSF;
        float s2 = d0*d0;
        s2 = fmaf(d1, d1, s2);
        s2 = fmaf(d2, d2, s2);
        s2 = fmaf(d3, d3, s2);
        s2 = fmaf(d4, d4, s2);
        s2 = fmaf(d5, d5, s2);
        s2 = fmaf(d6, d6, s2);
        s2 = fmaf(d7, d7, s2);
        acc += __builtin_amdgcn_sqrtf(s2);
    }
    float s = block_reduce_f(acc, red);
    if (threadIdx.x == 0) part[blockIdx.x] = s;
}

// Final: double-precision reduce of partials, subtract trace, compose scalar.
__global__ __launch_bounds__(256) void final_kernel(const float* __restrict__ alpha,
                                                    const float* __restrict__ dpart,
                                                    const float* __restrict__ spart,
                                                    float* __restrict__ out) {
    __shared__ double rd[4], rs[4];
    double ds = 0.0, ss = 0.0;
    for (int k = threadIdx.x; k < NDP; k += blockDim.x)       ds += (double)dpart[k];
    for (int k = threadIdx.x; k < SPARSE_NB; k += blockDim.x) ss += (double)spart[k];
    #pragma unroll
    for (int off = 32; off > 0; off >>= 1) {
        ds += __shfl_down(ds, off, 64);
        ss += __shfl_down(ss, off, 64);
    }
    int lane = threadIdx.x & 63, wid = threadIdx.x >> 6;
    if (lane == 0) { rd[wid] = ds; rs[wid] = ss; }
    __syncthreads();
    if (threadIdx.x == 0) {
        double Dsum = 0.0, Ssum = 0.0;
        for (int w = 0; w < 4; ++w) { Dsum += rd[w]; Ssum += rs[w]; }
        // subtract exact trace: all diagonal entries are exp(-sqrt(8)*eps)
        double trace = (double)S * exp(-sqrt(8.0) * (double)EPSF);
        double offdiag = Dsum - trace;
        double a = (double)alpha[0];
        double z_pdist2 = (double)NEDGES * a - Ssum;
        double z_pdist1 = exp(a) * 0.5 * 7.3890560989306495 * offdiag;
        out[0] = (float)(z_pdist2 - z_pdist1);
    }
}

extern "C" void kernel_launch(void* const* d_in, const int* in_sizes, int n_in,
                              void* d_out, int out_size, void* d_ws, size_t ws_size,
                              hipStream_t stream) {
    const float* latent_Z = (const float*)d_in[0];
    const float* alpha    = (const float*)d_in[1];
    const int*   sidx     = (const int*)d_in[2];
    const int*   ei       = (const int*)d_in[3];
    const int*   ej       = (const int*)d_in[4];
    float* out = (float*)d_out;
    char*  ws  = (char*)d_ws;

    ushort* zh    = (ushort*)(ws + ZH_OFF);
    ushort* zl    = (ushort*)(ws + ZL_OFF);
    float*  u     = (float*)(ws + U_OFF);
    float*  v     = (float*)(ws + V_OFF);
    float*  dpart = (float*)(ws + DP_OFF);
    float*  spart = (float*)(ws + SP_OFF);

    gather_kernel<<<S / 256, 256, 0, stream>>>(latent_Z, sidx, zh, zl, u, v);
    sparse_kernel<<<SPARSE_NB, 256, 0, stream>>>(latent_Z, ei, ej, spart);
    dense_kernel<<<dim3(512, JSPLIT), 256, 0, stream>>>(zh, zl, u, v, dpart);
    final_kernel<<<1, 256, 0, stream>>>(alpha, dpart, spart, out);
}

// Round 4
// 44.429 us; speedup vs baseline: 1.4825x; 1.1172x over previous
//
#include <hip/hip_runtime.h>
#include <hip/hip_bf16.h>
#include <math.h>

#define NNODES   100000
#define S        8192
#define D        8
#define EPSF     1e-6f
#define LOG2E    1.442695040888963f
#define EPS_S    (LOG2E * EPSF)

// ws byte offsets
#define ZHL_OFF  0          // 8192 rows x 16 ushort (hi[8]|lo[8]) = 262144 B
#define U_OFF    262144     // 8192 f32
#define V_OFF    294912     // 8192 f32
#define DP_OFF   327680     // 2048 f32 dense partials
#define SP_OFF   335872     // 256 f32 sparse partials

#define NSB      256        // sparse blocks (scheduled first)
#define NDB      2048       // dense blocks
#define NDP      2048

typedef __attribute__((ext_vector_type(8))) short short8_t;
typedef __attribute__((ext_vector_type(4))) float f32x4;

__device__ __forceinline__ float block_reduce_f(float v, float* sm) {
    #pragma unroll
    for (int off = 32; off > 0; off >>= 1) v += __shfl_down(v, off, 64);
    int lane = threadIdx.x & 63, wid = threadIdx.x >> 6;
    if (lane == 0) sm[wid] = v;
    __syncthreads();
    float s = 0.f;
    if (threadIdx.x == 0) {
        for (int w = 0; w < 4; ++w) s += sm[w];
    }
    return s;
}

// Gather sampled rows, prescale by log2e, split into bf16 hi+lo (interleaved
// row layout [hi x8 | lo x8]), precompute scaled u_i, v_j.
__global__ __launch_bounds__(256) void gather_kernel(const float* __restrict__ Z,
                                                     const int* __restrict__ idx,
                                                     ushort* __restrict__ zhl,
                                                     float* __restrict__ u,
                                                     float* __restrict__ v) {
    int t = blockIdx.x * 256 + threadIdx.x;
    if (t >= S) return;
    int n = idx[t];
    const float4* zp = (const float4*)(Z + (size_t)n * D);
    float4 a = zp[0], b = zp[1];
    float z[8] = { a.x, a.y, a.z, a.w, b.x, b.y, b.z, b.w };
    float ss = 0.f, sl = 0.f;
    short8_t h, l;
    #pragma unroll
    for (int k = 0; k < 8; ++k) {
        float zs = LOG2E * z[k];
        ss = fmaf(zs, zs, ss);
        sl += zs;
        __hip_bfloat16 hb = __float2bfloat16(zs);
        float hf = __bfloat162float(hb);
        __hip_bfloat16 lb = __float2bfloat16(zs - hf);
        h[k] = (short)__builtin_bit_cast(unsigned short, hb);
        l[k] = (short)__builtin_bit_cast(unsigned short, lb);
    }
    *(short8_t*)(zhl + (size_t)t * 16)     = h;
    *(short8_t*)(zhl + (size_t)t * 16 + 8) = l;
    u[t] = ss + 2.f * EPS_S * sl + 8.f * EPS_S * EPS_S;
    v[t] = ss - 2.f * EPS_S * sl;
}

// Fused: blocks [0,NSB) do the sparse edge term; blocks [NSB, NSB+NDB) do the
// dense term. Sparse is L2-latency-bound, dense is trans-pipe-bound -> overlap.
__global__ __launch_bounds__(256) void fused_kernel(const ushort* __restrict__ zhl,
                                                    const float* __restrict__ u,
                                                    const float* __restrict__ v,
                                                    const float* __restrict__ Z,
                                                    const int* __restrict__ ei,
                                                    const int* __restrict__ ej,
                                                    float* __restrict__ dpart,
                                                    float* __restrict__ spart,
                                                    int ne) {
    __shared__ float red[4];
    int tid = threadIdx.x;
    int bx  = blockIdx.x;

    if (bx < NSB) {
        // ---- sparse positive-edge term ----
        float acc = 0.f;
        int nchunk = ne >> 2;
        for (int c = bx * 256 + tid; c < nchunk; c += NSB * 256) {
            int4 ia = ((const int4*)ei)[c];
            int4 ib = ((const int4*)ej)[c];
            int aidx[4] = { ia.x, ia.y, ia.z, ia.w };
            int bidx[4] = { ib.x, ib.y, ib.z, ib.w };
            #pragma unroll
            for (int q = 0; q < 4; ++q) {
                const float4* za = (const float4*)(Z + (size_t)aidx[q] * D);
                const float4* zb = (const float4*)(Z + (size_t)bidx[q] * D);
                float4 a0 = za[0], a1 = za[1];
                float4 b0 = zb[0], b1 = zb[1];
                float d0 = a0.x - b0.x + EPSF;
                float d1 = a0.y - b0.y + EPSF;
                float d2 = a0.z - b0.z + EPSF;
                float d3 = a0.w - b0.w + EPSF;
                float d4 = a1.x - b1.x + EPSF;
                float d5 = a1.y - b1.y + EPSF;
                float d6 = a1.z - b1.z + EPSF;
                float d7 = a1.w - b1.w + EPSF;
                float s2 = d0 * d0;
                s2 = fmaf(d1, d1, s2);
                s2 = fmaf(d2, d2, s2);
                s2 = fmaf(d3, d3, s2);
                s2 = fmaf(d4, d4, s2);
                s2 = fmaf(d5, d5, s2);
                s2 = fmaf(d6, d6, s2);
                s2 = fmaf(d7, d7, s2);
                acc += __builtin_amdgcn_sqrtf(s2);
            }
        }
        // tail (ne % 4)
        for (int e = (nchunk << 2) + bx * 256 + tid; e < ne; e += NSB * 256) {
            int a = ei[e], b = ej[e];
            const float4* za = (const float4*)(Z + (size_t)a * D);
            const float4* zb = (const float4*)(Z + (size_t)b * D);
            float4 a0 = za[0], a1 = za[1];
            float4 b0 = zb[0], b1 = zb[1];
            float d0 = a0.x - b0.x + EPSF, d1 = a0.y - b0.y + EPSF;
            float d2 = a0.z - b0.z + EPSF, d3 = a0.w - b0.w + EPSF;
            float d4 = a1.x - b1.x + EPSF, d5 = a1.y - b1.y + EPSF;
            float d6 = a1.z - b1.z + EPSF, d7 = a1.w - b1.w + EPSF;
            float s2 = d0 * d0;
            s2 = fmaf(d1, d1, s2); s2 = fmaf(d2, d2, s2); s2 = fmaf(d3, d3, s2);
            s2 = fmaf(d4, d4, s2); s2 = fmaf(d5, d5, s2); s2 = fmaf(d6, d6, s2);
            s2 = fmaf(d7, d7, s2);
            acc += __builtin_amdgcn_sqrtf(s2);
        }
        float s = block_reduce_f(acc, red);
        if (tid == 0) spart[bx] = s;
        return;
    }

    // ---- dense term ----
    int dbx  = bx - NSB;
    int wave = tid >> 6, lane = tid & 63;
    int g = lane >> 4, r = lane & 15;

    int ib = dbx >> 2, by = dbx & 3;
    int i0  = ib * 16;
    int jt0 = by * 128 + wave * 32;

    // A fragment: row i0+r; k-group g even -> hi, odd -> lo
    short8_t afrag = *(const short8_t*)(zhl + (size_t)(i0 + r) * 16 + (g & 1) * 8);
    // C rows for this lane: i = i0 + g*4 + q
    float4 u4 = *(const float4*)(u + i0 + g * 4);
    // B fragment base: k-group g<2 -> hi, g>=2 -> lo
    int boff = (g >> 1) * 8;

    int j0 = jt0 * 16;
    const ushort* bp = zhl + (size_t)(j0 + r) * 16 + boff;
    const float*  vp = v + j0 + r;

    short8_t bnext = *(const short8_t*)bp;
    float    vnext = vp[0];

    float ax = 0.f, ay = 0.f, az = 0.f, aw = 0.f;
    #pragma unroll 4
    for (int t = 0; t < 32; ++t) {
        short8_t bcur = bnext;
        float    vcur = vnext;
        if (t < 31) {
            bnext = *(const short8_t*)(bp + (size_t)(t + 1) * 256);
            vnext = vp[(t + 1) * 16];
        }
        f32x4 c = { 0.f, 0.f, 0.f, 0.f };
        c = __builtin_amdgcn_mfma_f32_16x16x32_bf16(afrag, bcur, c, 0, 0, 0);
        float d2_0 = fmaxf(fmaf(c[0], -2.f, u4.x + vcur), 0.f);
        float d2_1 = fmaxf(fmaf(c[1], -2.f, u4.y + vcur), 0.f);
        float d2_2 = fmaxf(fmaf(c[2], -2.f, u4.z + vcur), 0.f);
        float d2_3 = fmaxf(fmaf(c[3], -2.f, u4.w + vcur), 0.f);
        ax += __builtin_amdgcn_exp2f(-__builtin_amdgcn_sqrtf(d2_0));
        ay += __builtin_amdgcn_exp2f(-__builtin_amdgcn_sqrtf(d2_1));
        az += __builtin_amdgcn_exp2f(-__builtin_amdgcn_sqrtf(d2_2));
        aw += __builtin_amdgcn_exp2f(-__builtin_amdgcn_sqrtf(d2_3));
    }

    float s = block_reduce_f((ax + ay) + (az + aw), red);
    if (tid == 0) dpart[dbx] = s;
}

// Final: double-precision reduce of partials, subtract analytic trace, compose.
__global__ __launch_bounds__(256) void final_kernel(const float* __restrict__ alpha,
                                                    const float* __restrict__ dpart,
                                                    const float* __restrict__ spart,
                                                    float* __restrict__ out,
                                                    int ne) {
    __shared__ double rd[4], rs[4];
    double ds = 0.0, ss = 0.0;
    for (int k = threadIdx.x; k < NDP; k += blockDim.x) ds += (double)dpart[k];
    for (int k = threadIdx.x; k < NSB; k += blockDim.x) ss += (double)spart[k];
    #pragma unroll
    for (int off = 32; off > 0; off >>= 1) {
        ds += __shfl_down(ds, off, 64);
        ss += __shfl_down(ss, off, 64);
    }
    int lane = threadIdx.x & 63, wid = threadIdx.x >> 6;
    if (lane == 0) { rd[wid] = ds; rs[wid] = ss; }
    __syncthreads();
    if (threadIdx.x == 0) {
        double Dsum = 0.0, Ssum = 0.0;
        for (int w = 0; w < 4; ++w) { Dsum += rd[w]; Ssum += rs[w]; }
        // all diagonal entries are exp(-sqrt(8)*eps); subtract exactly
        double trace = (double)S * exp(-sqrt(8.0) * (double)EPSF);
        double offdiag = Dsum - trace;
        double a = (double)alpha[0];
        double z_pdist2 = (double)ne * a - Ssum;
        double z_pdist1 = exp(a) * 0.5 * 7.3890560989306495 * offdiag;
        out[0] = (float)(z_pdist2 - z_pdist1);
    }
}

extern "C" void kernel_launch(void* const* d_in, const int* in_sizes, int n_in,
                              void* d_out, int out_size, void* d_ws, size_t ws_size,
                              hipStream_t stream) {
    const float* latent_Z = (const float*)d_in[0];
    const float* alpha    = (const float*)d_in[1];
    const int*   sidx     = (const int*)d_in[2];
    const int*   ei       = (const int*)d_in[3];
    const int*   ej       = (const int*)d_in[4];
    int ne = in_sizes[3];
    float* out = (float*)d_out;
    char*  ws  = (char*)d_ws;

    ushort* zhl   = (ushort*)(ws + ZHL_OFF);
    float*  u     = (float*)(ws + U_OFF);
    float*  v     = (float*)(ws + V_OFF);
    float*  dpart = (float*)(ws + DP_OFF);
    float*  spart = (float*)(ws + SP_OFF);

    gather_kernel<<<S / 256, 256, 0, stream>>>(latent_Z, sidx, zhl, u, v);
    fused_kernel<<<NSB + NDB, 256, 0, stream>>>(zhl, u, v, latent_Z, ei, ej,
                                                dpart, spart, ne);
    final_kernel<<<1, 256, 0, stream>>>(alpha, dpart, spart, out, ne);
}

// Round 5
// 37.710 us; speedup vs baseline: 1.7467x; 1.1782x over previous
//
#include <hip/hip_runtime.h>
#include <hip/hip_bf16.h>
#include <math.h>

#define NNODES   100000
#define S        8192
#define D        8
#define EPSF     1e-6f
#define LOG2E    1.442695040888963f
#define EPS_S    (LOG2E * EPSF)

// ws byte offsets
#define ZHL_OFF  0          // 8192 rows x 16 ushort (hi[8]|lo[8]) = 262144 B
#define U_OFF    262144     // 8192 f32
#define V_OFF    294912     // 8192 f32
#define DP_OFF   327680     // 2048 f32 dense partials
#define SP_OFF   335872     // 256 f32 sparse partials

#define NSB      256        // sparse blocks
#define NDB      2048       // dense blocks
#define NDP      2048
#define NT       512        // 8192/16 tiles per dim

typedef __attribute__((ext_vector_type(8))) short short8_t;
typedef __attribute__((ext_vector_type(4))) float f32x4;

__device__ __forceinline__ float block_reduce_f(float v, float* sm) {
    #pragma unroll
    for (int off = 32; off > 0; off >>= 1) v += __shfl_down(v, off, 64);
    int lane = threadIdx.x & 63, wid = threadIdx.x >> 6;
    if (lane == 0) sm[wid] = v;
    __syncthreads();
    float s = 0.f;
    if (threadIdx.x == 0) {
        for (int w = 0; w < 4; ++w) s += sm[w];
    }
    return s;
}

// Gather sampled rows, prescale by log2e, split into bf16 hi+lo (row layout
// [hi x8 | lo x8]), precompute symmetric-form u_i = ||z||^2 + 8eps^2, v_j = ||z||^2.
__global__ __launch_bounds__(256) void gather_kernel(const float* __restrict__ Z,
                                                     const int* __restrict__ idx,
                                                     ushort* __restrict__ zhl,
                                                     float* __restrict__ u,
                                                     float* __restrict__ v) {
    int t = blockIdx.x * 256 + threadIdx.x;
    if (t >= S) return;
    int n = idx[t];
    const float4* zp = (const float4*)(Z + (size_t)n * D);
    float4 a = zp[0], b = zp[1];
    float z[8] = { a.x, a.y, a.z, a.w, b.x, b.y, b.z, b.w };
    float ss = 0.f;
    short8_t h, l;
    #pragma unroll
    for (int k = 0; k < 8; ++k) {
        float zs = LOG2E * z[k];
        ss = fmaf(zs, zs, ss);
        __hip_bfloat16 hb = __float2bfloat16(zs);
        float hf = __bfloat162float(hb);
        __hip_bfloat16 lb = __float2bfloat16(zs - hf);
        h[k] = (short)__builtin_bit_cast(unsigned short, hb);
        l[k] = (short)__builtin_bit_cast(unsigned short, lb);
    }
    *(short8_t*)(zhl + (size_t)t * 16)     = h;
    *(short8_t*)(zhl + (size_t)t * 16 + 8) = l;
    u[t] = ss + 8.f * EPS_S * EPS_S;
    v[t] = ss;
}

// Sweep `cnt` consecutive j-tiles starting at tj0 for fixed i-tile ti.
// Off-diagonal tiles get weight 2 (mirror tile not enumerated), diag weight 1.
__device__ __forceinline__ void dense_sweep(const ushort* __restrict__ zhl,
                                            const float* __restrict__ v,
                                            short8_t afrag, float4 u4, int boff,
                                            int ti, int tj0, int cnt, int r,
                                            float& ax, float& ay, float& az, float& aw) {
    const ushort* bp = zhl + (size_t)(tj0 * 16 + r) * 16 + boff;
    const float*  vp = v + tj0 * 16 + r;
    short8_t bnext = *(const short8_t*)bp;
    float    vnext = vp[0];
    #pragma unroll 4
    for (int t = 0; t < cnt; ++t) {
        short8_t bcur = bnext;
        float    vcur = vnext;
        if (t + 1 < cnt) {
            bnext = *(const short8_t*)(bp + (size_t)(t + 1) * 256);
            vnext = vp[(t + 1) * 16];
        }
        float w = (tj0 + t == ti) ? 1.f : 2.f;
        f32x4 c = { 0.f, 0.f, 0.f, 0.f };
        c = __builtin_amdgcn_mfma_f32_16x16x32_bf16(afrag, bcur, c, 0, 0, 0);
        float d2_0 = fmaf(c[0], -2.f, u4.x + vcur);
        float d2_1 = fmaf(c[1], -2.f, u4.y + vcur);
        float d2_2 = fmaf(c[2], -2.f, u4.z + vcur);
        float d2_3 = fmaf(c[3], -2.f, u4.w + vcur);
        ax = fmaf(w, __builtin_amdgcn_exp2f(-__builtin_amdgcn_sqrtf(__builtin_fabsf(d2_0))), ax);
        ay = fmaf(w, __builtin_amdgcn_exp2f(-__builtin_amdgcn_sqrtf(__builtin_fabsf(d2_1))), ay);
        az = fmaf(w, __builtin_amdgcn_exp2f(-__builtin_amdgcn_sqrtf(__builtin_fabsf(d2_2))), az);
        aw = fmaf(w, __builtin_amdgcn_exp2f(-__builtin_amdgcn_sqrtf(__builtin_fabsf(d2_3))), aw);
    }
}

// Fused: blocks [0,NSB) sparse edge term; blocks [NSB, NSB+NDB) dense term
// over the upper triangle of 16x16 tiles with row-pair load balancing:
// block-group pb handles rows {pb, 511-pb} -> exactly 513 tiles, split over
// 32 waves (8 blocks x 4 waves) as contiguous chunks.
__global__ __launch_bounds__(256) void fused_kernel(const ushort* __restrict__ zhl,
                                                    const float* __restrict__ u,
                                                    const float* __restrict__ v,
                                                    const float* __restrict__ Z,
                                                    const int* __restrict__ ei,
                                                    const int* __restrict__ ej,
                                                    float* __restrict__ dpart,
                                                    float* __restrict__ spart,
                                                    int ne) {
    __shared__ float red[4];
    int tid = threadIdx.x;
    int bx  = blockIdx.x;

    if (bx < NSB) {
        // ---- sparse positive-edge term ----
        float acc = 0.f;
        int nchunk = ne >> 2;
        for (int c = bx * 256 + tid; c < nchunk; c += NSB * 256) {
            int4 ia = ((const int4*)ei)[c];
            int4 ib = ((const int4*)ej)[c];
            int aidx[4] = { ia.x, ia.y, ia.z, ia.w };
            int bidx[4] = { ib.x, ib.y, ib.z, ib.w };
            #pragma unroll
            for (int q = 0; q < 4; ++q) {
                const float4* za = (const float4*)(Z + (size_t)aidx[q] * D);
                const float4* zb = (const float4*)(Z + (size_t)bidx[q] * D);
                float4 a0 = za[0], a1 = za[1];
                float4 b0 = zb[0], b1 = zb[1];
                float d0 = a0.x - b0.x + EPSF;
                float d1 = a0.y - b0.y + EPSF;
                float d2 = a0.z - b0.z + EPSF;
                float d3 = a0.w - b0.w + EPSF;
                float d4 = a1.x - b1.x + EPSF;
                float d5 = a1.y - b1.y + EPSF;
                float d6 = a1.z - b1.z + EPSF;
                float d7 = a1.w - b1.w + EPSF;
                float s2 = d0 * d0;
                s2 = fmaf(d1, d1, s2);
                s2 = fmaf(d2, d2, s2);
                s2 = fmaf(d3, d3, s2);
                s2 = fmaf(d4, d4, s2);
                s2 = fmaf(d5, d5, s2);
                s2 = fmaf(d6, d6, s2);
                s2 = fmaf(d7, d7, s2);
                acc += __builtin_amdgcn_sqrtf(s2);
            }
        }
        for (int e = (nchunk << 2) + bx * 256 + tid; e < ne; e += NSB * 256) {
            int a = ei[e], b = ej[e];
            const float4* za = (const float4*)(Z + (size_t)a * D);
            const float4* zb = (const float4*)(Z + (size_t)b * D);
            float4 a0 = za[0], a1 = za[1];
            float4 b0 = zb[0], b1 = zb[1];
            float d0 = a0.x - b0.x + EPSF, d1 = a0.y - b0.y + EPSF;
            float d2 = a0.z - b0.z + EPSF, d3 = a0.w - b0.w + EPSF;
            float d4 = a1.x - b1.x + EPSF, d5 = a1.y - b1.y + EPSF;
            float d6 = a1.z - b1.z + EPSF, d7 = a1.w - b1.w + EPSF;
            float s2 = d0 * d0;
            s2 = fmaf(d1, d1, s2); s2 = fmaf(d2, d2, s2); s2 = fmaf(d3, d3, s2);
            s2 = fmaf(d4, d4, s2); s2 = fmaf(d5, d5, s2); s2 = fmaf(d6, d6, s2);
            s2 = fmaf(d7, d7, s2);
            acc += __builtin_amdgcn_sqrtf(s2);
        }
        float s = block_reduce_f(acc, red);
        if (tid == 0) spart[bx] = s;
        return;
    }

    // ---- dense term (upper-triangle tiles, row-paired) ----
    int dbx  = bx - NSB;
    int wave = tid >> 6, lane = tid & 63;
    int g = lane >> 4, r = lane & 15;

    int pb = dbx >> 3;                       // row-pair index [0,256)
    int wv = (dbx & 7) * 4 + wave;           // wave within row-pair [0,32)
    int k0 = (wv * 513) >> 5;
    int k1 = ((wv + 1) * 513) >> 5;
    int n1 = NT - pb;                        // tiles in row r1 = pb

    int boff = (g >> 1) * 8;                 // B k-group: g<2 -> hi, g>=2 -> lo

    float ax = 0.f, ay = 0.f, az = 0.f, aw = 0.f;

    // segment A: row r1 = pb, k in [k0, min(k1,n1)), tj = pb + k
    int eA = k1 < n1 ? k1 : n1;
    if (k0 < eA) {
        int ti = pb;
        short8_t afrag = *(const short8_t*)(zhl + (size_t)(ti * 16 + r) * 16 + (g & 1) * 8);
        float4 u4 = *(const float4*)(u + ti * 16 + g * 4);
        dense_sweep(zhl, v, afrag, u4, boff, ti, pb + k0, eA - k0, r, ax, ay, az, aw);
    }
    // segment B: row r2 = 511-pb, k in [max(k0,n1), k1), tj = r2 + (k - n1)
    int sB = k0 > n1 ? k0 : n1;
    if (sB < k1) {
        int ti = (NT - 1) - pb;
        short8_t afrag = *(const short8_t*)(zhl + (size_t)(ti * 16 + r) * 16 + (g & 1) * 8);
        float4 u4 = *(const float4*)(u + ti * 16 + g * 4);
        dense_sweep(zhl, v, afrag, u4, boff, ti, ti + (sB - n1), k1 - sB, r, ax, ay, az, aw);
    }

    float s = block_reduce_f((ax + ay) + (az + aw), red);
    if (tid == 0) dpart[dbx] = s;
}

// Final: double-precision reduce of partials, subtract analytic trace, compose.
__global__ __launch_bounds__(256) void final_kernel(const float* __restrict__ alpha,
                                                    const float* __restrict__ dpart,
                                                    const float* __restrict__ spart,
                                                    float* __restrict__ out,
                                                    int ne) {
    __shared__ double rd[4], rs[4];
    double ds = 0.0, ss = 0.0;
    for (int k = threadIdx.x; k < NDP; k += blockDim.x) ds += (double)dpart[k];
    for (int k = threadIdx.x; k < NSB; k += blockDim.x) ss += (double)spart[k];
    #pragma unroll
    for (int off = 32; off > 0; off >>= 1) {
        ds += __shfl_down(ds, off, 64);
        ss += __shfl_down(ss, off, 64);
    }
    int lane = threadIdx.x & 63, wid = threadIdx.x >> 6;
    if (lane == 0) { rd[wid] = ds; rs[wid] = ss; }
    __syncthreads();
    if (threadIdx.x == 0) {
        double Dsum = 0.0, Ssum = 0.0;
        for (int w = 0; w < 4; ++w) { Dsum += rd[w]; Ssum += rs[w]; }
        // diagonal entries are exp(-sqrt(8)*eps); subtract exactly
        double trace = (double)S * exp(-sqrt(8.0) * (double)EPSF);
        double offdiag = Dsum - trace;
        double a = (double)alpha[0];
        double z_pdist2 = (double)ne * a - Ssum;
        double z_pdist1 = exp(a) * 0.5 * 7.3890560989306495 * offdiag;
        out[0] = (float)(z_pdist2 - z_pdist1);
    }
}

extern "C" void kernel_launch(void* const* d_in, const int* in_sizes, int n_in,
                              void* d_out, int out_size, void* d_ws, size_t ws_size,
                              hipStream_t stream) {
    const float* latent_Z = (const float*)d_in[0];
    const float* alpha    = (const float*)d_in[1];
    const int*   sidx     = (const int*)d_in[2];
    const int*   ei       = (const int*)d_in[3];
    const int*   ej       = (const int*)d_in[4];
    int ne = in_sizes[3];
    float* out = (float*)d_out;
    char*  ws  = (char*)d_ws;

    ushort* zhl   = (ushort*)(ws + ZHL_OFF);
    float*  u     = (float*)(ws + U_OFF);
    float*  v     = (float*)(ws + V_OFF);
    float*  dpart = (float*)(ws + DP_OFF);
    float*  spart = (float*)(ws + SP_OFF);

    gather_kernel<<<S / 256, 256, 0, stream>>>(latent_Z, sidx, zhl, u, v);
    fused_kernel<<<NSB + NDB, 256, 0, stream>>>(zhl, u, v, latent_Z, ei, ej,
                                                dpart, spart, ne);
    final_kernel<<<1, 256, 0, stream>>>(alpha, dpart, spart, out, ne);
}